// Round 7
// baseline (358.780 us; speedup 1.0000x reference)
//
#include <hip/hip_runtime.h>
#include <math.h>

#define N_NODES 100000
#define N_EDGES 1600000
#define N_GRAPHS 256
#define IN_F 64
#define H_F 128
#define GN_EPS 1e-5f
#define PAD 64
#define NBINS 8
#define LCAP 512
#define BINCAP (1 << 18)

__device__ __forceinline__ float bf2f(unsigned short u) {
  return __uint_as_float(((unsigned int)u) << 16);
}
__device__ __forceinline__ unsigned short f2bf(float f) {
  unsigned int u = __float_as_uint(f);
  u += 0x7FFFu + ((u >> 16) & 1u);
  return (unsigned short)(u >> 16);
}

// ---- cast x to bf16 (RTNE) ----
__global__ __launch_bounds__(256) void k_cast(const float4* __restrict__ in,
                                              ushort4* __restrict__ out, int n4) {
  int i = blockIdx.x * 256 + threadIdx.x;
  if (i < n4) {
    float4 v = in[i];
    ushort4 o;
    o.x = f2bf(v.x); o.y = f2bf(v.y); o.z = f2bf(v.z); o.w = f2bf(v.w);
    out[i] = o;
  }
}

// ---- phase A: LDS-staged radix partition of edges into 8 dst-range bins ----
__global__ __launch_bounds__(256) void k_bin(
    const int* __restrict__ src, const int* __restrict__ dst,
    unsigned long long* __restrict__ binBuf, int* __restrict__ gbc) {
  __shared__ unsigned long long ebuf[NBINS][LCAP];
  __shared__ int lcnt[NBINS];
  __shared__ int lbase[NBINS];
  const int t = threadIdx.x;
  if (t < NBINS) lcnt[t] = 0;
  __syncthreads();
  for (int e0 = blockIdx.x * 256; e0 < N_EDGES; e0 += gridDim.x * 256) {
    int e = e0 + t;
    if (e < N_EDGES) {
      int s = src[e], d = dst[e];
      int b = d / 12500;
      int p = atomicAdd(&lcnt[b], 1);
      ebuf[b][p] = ((unsigned long long)(unsigned)d << 32) | (unsigned)s;
    }
    __syncthreads();
    if (t < NBINS && lcnt[t] >= 256) lbase[t] = atomicAdd(&gbc[t], lcnt[t]);
    __syncthreads();
#pragma unroll
    for (int b = 0; b < NBINS; ++b) {
      int c = lcnt[b];
      if (c >= 256) {
        unsigned long long* gp = binBuf + (size_t)b * BINCAP + lbase[b];
        for (int i = t; i < c; i += 256) gp[i] = ebuf[b][i];
      }
    }
    __syncthreads();
    if (t < NBINS && lcnt[t] >= 256) lcnt[t] = 0;
    __syncthreads();
  }
  if (t < NBINS && lcnt[t] > 0) lbase[t] = atomicAdd(&gbc[t], lcnt[t]);
  __syncthreads();
#pragma unroll
  for (int b = 0; b < NBINS; ++b) {
    int c = lcnt[b];
    if (c > 0) {
      unsigned long long* gp = binBuf + (size_t)b * BINCAP + lbase[b];
      for (int i = t; i < c; i += 256) gp[i] = ebuf[b][i];
    }
  }
}

// ---- phase B: bucket fill, bin-per-XCD ----
__global__ __launch_bounds__(256) void k_fill2(
    const unsigned long long* __restrict__ binBuf, const int* __restrict__ gbc,
    int* __restrict__ csr, int* __restrict__ cnt,
    int* __restrict__ ovfc, int* __restrict__ ovf) {
  const int b = blockIdx.x & 7;
  const int nb = gbc[b];
  const unsigned long long* buf = binBuf + (size_t)b * BINCAP;
  const int stride = (gridDim.x >> 3) * 256;
  for (int i = (blockIdx.x >> 3) * 256 + threadIdx.x; i < nb; i += stride) {
    unsigned long long pk = buf[i];
    int d = (int)(pk >> 32), s = (int)(pk & 0xffffffffu);
    int pos = atomicAdd(&cnt[d], 1);
    if (pos < PAD) {
      csr[(size_t)d * PAD + pos] = s;
    } else {
      int o = atomicAdd(ovfc, 1);
      ovf[2 * o] = s;
      ovf[2 * o + 1] = d;
    }
  }
}

// ---- gather (bf16 x): wave per node; 16-lane group per src row ----
__global__ __launch_bounds__(256) void k_gather(
    const unsigned short* __restrict__ xh, const int* __restrict__ csr,
    const int* __restrict__ cnt, float* __restrict__ agg) {
  int wid = (blockIdx.x * 256 + threadIdx.x) >> 6;
  if (wid >= N_NODES) return;
  const int lane = threadIdx.x & 63;
  const int g = lane >> 4;
  const int fl = lane & 15;
  int deg = cnt[wid];
  if (deg > PAD) deg = PAD;
  int myE = csr[(size_t)wid * PAD + lane];
  float s0 = 0.f, s1 = 0.f, s2 = 0.f, s3 = 0.f;
  int j = g;
  for (; j + 4 < deg; j += 8) {
    int sA = __shfl(myE, j);
    int sB = __shfl(myE, j + 4);
    ushort4 a = *(const ushort4*)&xh[(size_t)sA * IN_F + fl * 4];
    ushort4 b = *(const ushort4*)&xh[(size_t)sB * IN_F + fl * 4];
    s0 += bf2f(a.x) + bf2f(b.x);
    s1 += bf2f(a.y) + bf2f(b.y);
    s2 += bf2f(a.z) + bf2f(b.z);
    s3 += bf2f(a.w) + bf2f(b.w);
  }
  if (j < deg) {
    int sA = __shfl(myE, j);
    ushort4 a = *(const ushort4*)&xh[(size_t)sA * IN_F + fl * 4];
    s0 += bf2f(a.x); s1 += bf2f(a.y); s2 += bf2f(a.z); s3 += bf2f(a.w);
  }
  s0 += __shfl_xor(s0, 16); s1 += __shfl_xor(s1, 16);
  s2 += __shfl_xor(s2, 16); s3 += __shfl_xor(s3, 16);
  s0 += __shfl_xor(s0, 32); s1 += __shfl_xor(s1, 32);
  s2 += __shfl_xor(s2, 32); s3 += __shfl_xor(s3, 32);
  if (g == 0) {
    float4 r = make_float4(s0, s1, s2, s3);
    *(float4*)&agg[(size_t)wid * IN_F + fl * 4] = r;
  }
}

// ---- overflow cleanup ----
__global__ __launch_bounds__(256) void k_ovf(
    const int* __restrict__ ovf, const int* __restrict__ ovfc,
    const float* __restrict__ x, float* __restrict__ agg) {
  int n = *ovfc;
  for (int idx = blockIdx.x * 256 + threadIdx.x; idx < n * 64; idx += gridDim.x * 256) {
    int o = idx >> 6, f = idx & 63;
    int s = ovf[2 * o], d = ovf[2 * o + 1];
    unsafeAtomicAdd(&agg[(size_t)d * IN_F + f], x[(size_t)s * IN_F + f]);
  }
}

// ============ GEMM v2: 128x128 tile, 8x8 per thread, XOR-swizzled A ============
// Thread map: u = t&15 (cols 4u and 64+4u), tg = t>>4 (rows 8*tg..8*tg+7).
// As[m][68]: k-chunk kq stored at col 4*(kq ^ ((m>>3)&7)) -> conflict-free
// b128 reads of 8 rows (8 apart) per thread. Ws[k][128] read at paired cols.

// ---- GEMM1: out = relu((x+agg) @ W1 + b1), K=64, fp32 ----
__global__ __launch_bounds__(256) void k_gemm1v2(
    const float* __restrict__ xin, const float* __restrict__ agg,
    const float* __restrict__ W, const float* __restrict__ bias,
    float* __restrict__ out) {
  __shared__ __align__(16) float As[128 * 68];   // 34.8 KB
  __shared__ __align__(16) float Ws[64 * 128];   // 32 KB
  const int t = threadIdx.x;
  const int u = t & 15;
  const int tg = t >> 4;
  const int m0 = blockIdx.x * 128;
#pragma unroll
  for (int it = 0; it < 8; ++it) {
    int f = t + it * 256;          // 0..2047
    int m = f >> 4, kq = f & 15;
    int row = m0 + m; if (row > N_NODES - 1) row = N_NODES - 1;
    float4 a = *(const float4*)&xin[(size_t)row * IN_F + 4 * kq];
    float4 g = *(const float4*)&agg[(size_t)row * IN_F + 4 * kq];
    a.x += g.x; a.y += g.y; a.z += g.z; a.w += g.w;
    int col = 4 * (kq ^ ((m >> 3) & 7));
    *(float4*)&As[m * 68 + col] = a;
  }
#pragma unroll
  for (int it = 0; it < 8; ++it) {
    int f = t + it * 256;          // 0..2047
    int k = f >> 5, nq = f & 31;
    *(float4*)&Ws[k * 128 + 4 * nq] = *(const float4*)&W[(size_t)k * H_F + 4 * nq];
  }
  __syncthreads();
  float acc[8][8] = {};
  const int swz = tg & 7;
#pragma unroll 2
  for (int kg = 0; kg < 16; ++kg) {
    float a[8][4], bl[4][4], bh[4][4];
    int acol = 4 * (kg ^ swz);
#pragma unroll
    for (int i = 0; i < 8; ++i)
      *(float4*)&a[i][0] = *(const float4*)&As[(8 * tg + i) * 68 + acol];
#pragma unroll
    for (int kk = 0; kk < 4; ++kk) {
      *(float4*)&bl[kk][0] = *(const float4*)&Ws[(4 * kg + kk) * 128 + 4 * u];
      *(float4*)&bh[kk][0] = *(const float4*)&Ws[(4 * kg + kk) * 128 + 64 + 4 * u];
    }
#pragma unroll
    for (int i = 0; i < 8; ++i)
#pragma unroll
      for (int kk = 0; kk < 4; ++kk) {
        float av = a[i][kk];
#pragma unroll
        for (int j = 0; j < 4; ++j) {
          acc[i][j]     += av * bl[kk][j];
          acc[i][4 + j] += av * bh[kk][j];
        }
      }
  }
  float4 bvl = *(const float4*)&bias[4 * u];
  float4 bvh = *(const float4*)&bias[64 + 4 * u];
#pragma unroll
  for (int i = 0; i < 8; ++i) {
    int row = m0 + 8 * tg + i;
    if (row < N_NODES) {
      float4 lo, hi;
      lo.x = fmaxf(acc[i][0] + bvl.x, 0.f); lo.y = fmaxf(acc[i][1] + bvl.y, 0.f);
      lo.z = fmaxf(acc[i][2] + bvl.z, 0.f); lo.w = fmaxf(acc[i][3] + bvl.w, 0.f);
      hi.x = fmaxf(acc[i][4] + bvh.x, 0.f); hi.y = fmaxf(acc[i][5] + bvh.y, 0.f);
      hi.z = fmaxf(acc[i][6] + bvh.z, 0.f); hi.w = fmaxf(acc[i][7] + bvh.w, 0.f);
      *(float4*)&out[(size_t)row * H_F + 4 * u] = lo;
      *(float4*)&out[(size_t)row * H_F + 64 + 4 * u] = hi;
    }
  }
}

// ---- GEMM K=128 (+optional fused GraphNorm stats), fp32 ----
template <int STATS>
__global__ __launch_bounds__(256) void k_gemmB(
    const float* __restrict__ in, const float* __restrict__ W,
    const float* __restrict__ bias, float* __restrict__ out,
    const int* __restrict__ batch, float* __restrict__ gsum,
    float* __restrict__ gsumsq) {
  __shared__ __align__(16) float As[128 * 68];
  __shared__ __align__(16) float Ws[64 * 128];
  const int t = threadIdx.x;
  const int u = t & 15;
  const int tg = t >> 4;
  const int m0 = blockIdx.x * 128;
  float acc[8][8] = {};
  const int swz = tg & 7;
  for (int kh = 0; kh < 2; ++kh) {
    __syncthreads();
#pragma unroll
    for (int it = 0; it < 8; ++it) {
      int f = t + it * 256;
      int m = f >> 4, kq = f & 15;
      int row = m0 + m; if (row > N_NODES - 1) row = N_NODES - 1;
      float4 v = *(const float4*)&in[(size_t)row * H_F + kh * 64 + 4 * kq];
      int col = 4 * (kq ^ ((m >> 3) & 7));
      *(float4*)&As[m * 68 + col] = v;
    }
#pragma unroll
    for (int it = 0; it < 8; ++it) {
      int f = t + it * 256;
      int k = f >> 5, nq = f & 31;
      *(float4*)&Ws[k * 128 + 4 * nq] =
          *(const float4*)&W[(size_t)(kh * 64 + k) * H_F + 4 * nq];
    }
    __syncthreads();
#pragma unroll 2
    for (int kg = 0; kg < 16; ++kg) {
      float a[8][4], bl[4][4], bh[4][4];
      int acol = 4 * (kg ^ swz);
#pragma unroll
      for (int i = 0; i < 8; ++i)
        *(float4*)&a[i][0] = *(const float4*)&As[(8 * tg + i) * 68 + acol];
#pragma unroll
      for (int kk = 0; kk < 4; ++kk) {
        *(float4*)&bl[kk][0] = *(const float4*)&Ws[(4 * kg + kk) * 128 + 4 * u];
        *(float4*)&bh[kk][0] = *(const float4*)&Ws[(4 * kg + kk) * 128 + 64 + 4 * u];
      }
#pragma unroll
      for (int i = 0; i < 8; ++i)
#pragma unroll
        for (int kk = 0; kk < 4; ++kk) {
          float av = a[i][kk];
#pragma unroll
          for (int j = 0; j < 4; ++j) {
            acc[i][j]     += av * bl[kk][j];
            acc[i][4 + j] += av * bh[kk][j];
          }
        }
    }
  }
  // epilogue: bias + relu (in place in acc) + store
  float4 bvl = *(const float4*)&bias[4 * u];
  float4 bvh = *(const float4*)&bias[64 + 4 * u];
#pragma unroll
  for (int i = 0; i < 8; ++i) {
    acc[i][0] = fmaxf(acc[i][0] + bvl.x, 0.f); acc[i][1] = fmaxf(acc[i][1] + bvl.y, 0.f);
    acc[i][2] = fmaxf(acc[i][2] + bvl.z, 0.f); acc[i][3] = fmaxf(acc[i][3] + bvl.w, 0.f);
    acc[i][4] = fmaxf(acc[i][4] + bvh.x, 0.f); acc[i][5] = fmaxf(acc[i][5] + bvh.y, 0.f);
    acc[i][6] = fmaxf(acc[i][6] + bvh.z, 0.f); acc[i][7] = fmaxf(acc[i][7] + bvh.w, 0.f);
    int row = m0 + 8 * tg + i;
    if (row < N_NODES) {
      *(float4*)&out[(size_t)row * H_F + 4 * u] = *(float4*)&acc[i][0];
      *(float4*)&out[(size_t)row * H_F + 64 + 4 * u] = *(float4*)&acc[i][4];
    }
  }
  if (STATS) {
    const int glo = batch[m0];
    const int ghiIdx = (m0 + 127 < N_NODES) ? m0 + 127 : N_NODES - 1;
    const int ghi = batch[ghiIdx];
    if (glo == ghi) {
      float s[8] = {}, q[8] = {};
#pragma unroll
      for (int i = 0; i < 8; ++i) {
        int row = m0 + 8 * tg + i;
        if (row < N_NODES) {
#pragma unroll
          for (int j = 0; j < 8; ++j) { s[j] += acc[i][j]; q[j] += acc[i][j] * acc[i][j]; }
        }
      }
      __syncthreads();                 // done with As; reuse as scratch
      float4* SP = (float4*)&As[0];    // 4 arrays x [16 tg][16 u]
      SP[0 * 256 + tg * 16 + u] = *(float4*)&s[0];
      SP[1 * 256 + tg * 16 + u] = *(float4*)&s[4];
      SP[2 * 256 + tg * 16 + u] = *(float4*)&q[0];
      SP[3 * 256 + tg * 16 + u] = *(float4*)&q[4];
      __syncthreads();
      if (tg == 0) {                   // 16 threads, u = t
        float4 SL = {0,0,0,0}, SH = {0,0,0,0}, QL = {0,0,0,0}, QH = {0,0,0,0};
#pragma unroll
        for (int w = 0; w < 16; ++w) {
          float4 a0 = SP[0 * 256 + w * 16 + u]; SL.x += a0.x; SL.y += a0.y; SL.z += a0.z; SL.w += a0.w;
          float4 a1 = SP[1 * 256 + w * 16 + u]; SH.x += a1.x; SH.y += a1.y; SH.z += a1.z; SH.w += a1.w;
          float4 a2 = SP[2 * 256 + w * 16 + u]; QL.x += a2.x; QL.y += a2.y; QL.z += a2.z; QL.w += a2.w;
          float4 a3 = SP[3 * 256 + w * 16 + u]; QH.x += a3.x; QH.y += a3.y; QH.z += a3.z; QH.w += a3.w;
        }
        float* ps = &gsum[(size_t)glo * H_F];
        float* pq = &gsumsq[(size_t)glo * H_F];
        unsafeAtomicAdd(ps + 4 * u + 0, SL.x); unsafeAtomicAdd(ps + 4 * u + 1, SL.y);
        unsafeAtomicAdd(ps + 4 * u + 2, SL.z); unsafeAtomicAdd(ps + 4 * u + 3, SL.w);
        unsafeAtomicAdd(ps + 64 + 4 * u + 0, SH.x); unsafeAtomicAdd(ps + 64 + 4 * u + 1, SH.y);
        unsafeAtomicAdd(ps + 64 + 4 * u + 2, SH.z); unsafeAtomicAdd(ps + 64 + 4 * u + 3, SH.w);
        unsafeAtomicAdd(pq + 4 * u + 0, QL.x); unsafeAtomicAdd(pq + 4 * u + 1, QL.y);
        unsafeAtomicAdd(pq + 4 * u + 2, QL.z); unsafeAtomicAdd(pq + 4 * u + 3, QL.w);
        unsafeAtomicAdd(pq + 64 + 4 * u + 0, QH.x); unsafeAtomicAdd(pq + 64 + 4 * u + 1, QH.y);
        unsafeAtomicAdd(pq + 64 + 4 * u + 2, QH.z); unsafeAtomicAdd(pq + 64 + 4 * u + 3, QH.w);
      }
    } else {
      // graph boundary inside block: per-row tracking, flush on change
      float s[8] = {}, q[8] = {};
      int gcur = -1;
#pragma unroll
      for (int i = 0; i < 8; ++i) {
        int row = m0 + 8 * tg + i;
        if (row >= N_NODES) continue;
        int g = batch[row];
        if (g != gcur) {
          if (gcur >= 0) {
            float* ps = &gsum[(size_t)gcur * H_F];
            float* pq = &gsumsq[(size_t)gcur * H_F];
#pragma unroll
            for (int j = 0; j < 4; ++j) {
              unsafeAtomicAdd(ps + 4 * u + j, s[j]);
              unsafeAtomicAdd(ps + 64 + 4 * u + j, s[4 + j]);
              unsafeAtomicAdd(pq + 4 * u + j, q[j]);
              unsafeAtomicAdd(pq + 64 + 4 * u + j, q[4 + j]);
            }
#pragma unroll
            for (int j = 0; j < 8; ++j) { s[j] = 0.f; q[j] = 0.f; }
          }
          gcur = g;
        }
#pragma unroll
        for (int j = 0; j < 8; ++j) { s[j] += acc[i][j]; q[j] += acc[i][j] * acc[i][j]; }
      }
      if (gcur >= 0) {
        float* ps = &gsum[(size_t)gcur * H_F];
        float* pq = &gsumsq[(size_t)gcur * H_F];
#pragma unroll
        for (int j = 0; j < 4; ++j) {
          unsafeAtomicAdd(ps + 4 * u + j, s[j]);
          unsafeAtomicAdd(ps + 64 + 4 * u + j, s[4 + j]);
          unsafeAtomicAdd(pq + 4 * u + j, q[j]);
          unsafeAtomicAdd(pq + 64 + 4 * u + j, q[4 + j]);
        }
      }
    }
  }
}

// ---- finalize: per (graph,feature) shift/scale; init flat = -INF ----
__global__ __launch_bounds__(128) void k_finalize(
    const int* __restrict__ batch, const float* __restrict__ gsum,
    const float* __restrict__ gsumsq, const float* __restrict__ gms,
    const float* __restrict__ gw, float* __restrict__ msc,
    float* __restrict__ scale, float* __restrict__ flat) {
  const int g = blockIdx.x;
  const int f = threadIdx.x;
  __shared__ int sb[2];
  if (f < 2) {
    int target = g + f;
    int lo = 0, hi = N_NODES;
    while (lo < hi) { int mid = (lo + hi) >> 1; if (batch[mid] < target) lo = mid + 1; else hi = mid; }
    sb[f] = lo;
  }
  __syncthreads();
  float c = fmaxf((float)(sb[1] - sb[0]), 1.0f);
  float mean = gsum[(size_t)g * H_F + f] / c;
  float ms = mean * gms[f];
  float var = gsumsq[(size_t)g * H_F + f] / c - 2.0f * ms * mean + ms * ms;
  var = fmaxf(var, 0.0f);
  msc[(size_t)g * H_F + f] = ms;
  scale[(size_t)g * H_F + f] = gw[f] * rsqrtf(var + GN_EPS);
  flat[(size_t)g * H_F + f] = -INFINITY;
}

// ---- apply: h = relu((h - msc)*scale + gb); flat = segment max ----
__global__ __launch_bounds__(256) void k_apply(
    float* __restrict__ h, const int* __restrict__ batch,
    const float* __restrict__ msc, const float* __restrict__ scale,
    const float* __restrict__ gb, float* __restrict__ flat) {
  const int t = threadIdx.x;
  const int rg = t >> 5, fq = t & 31;
  const int m0 = blockIdx.x * 32;
  const int r0 = m0 + rg * 4;
  const float4 bb = *(const float4*)&gb[fq * 4];
  const int glo = batch[m0], ghi = batch[m0 + 31];
  __shared__ __align__(16) float4 mred[8][32];
  if (glo == ghi) {
    const float4 m = *(const float4*)&msc[(size_t)glo * H_F + fq * 4];
    const float4 sc = *(const float4*)&scale[(size_t)glo * H_F + fq * 4];
    float4 mx = {-INFINITY, -INFINITY, -INFINITY, -INFINITY};
#pragma unroll
    for (int i = 0; i < 4; ++i) {
      size_t idx = (size_t)(r0 + i) * H_F + fq * 4;
      float4 v = *(const float4*)&h[idx];
      v.x = fmaxf((v.x - m.x) * sc.x + bb.x, 0.f);
      v.y = fmaxf((v.y - m.y) * sc.y + bb.y, 0.f);
      v.z = fmaxf((v.z - m.z) * sc.z + bb.z, 0.f);
      v.w = fmaxf((v.w - m.w) * sc.w + bb.w, 0.f);
      *(float4*)&h[idx] = v;
      mx.x = fmaxf(mx.x, v.x); mx.y = fmaxf(mx.y, v.y);
      mx.z = fmaxf(mx.z, v.z); mx.w = fmaxf(mx.w, v.w);
    }
    mred[rg][fq] = mx;
    __syncthreads();
    if (rg == 0) {
#pragma unroll
      for (int j = 1; j < 8; ++j) {
        float4 a = mred[j][fq];
        mx.x = fmaxf(mx.x, a.x); mx.y = fmaxf(mx.y, a.y);
        mx.z = fmaxf(mx.z, a.z); mx.w = fmaxf(mx.w, a.w);
      }
      int* pf = (int*)&flat[(size_t)glo * H_F + fq * 4];
      atomicMax(pf + 0, __float_as_int(mx.x));
      atomicMax(pf + 1, __float_as_int(mx.y));
      atomicMax(pf + 2, __float_as_int(mx.z));
      atomicMax(pf + 3, __float_as_int(mx.w));
    }
  } else {
    int gcur = batch[r0];
    float4 mm = *(const float4*)&msc[(size_t)gcur * H_F + fq * 4];
    float4 ss = *(const float4*)&scale[(size_t)gcur * H_F + fq * 4];
    float4 mx = {-INFINITY, -INFINITY, -INFINITY, -INFINITY};
#pragma unroll
    for (int i = 0; i < 4; ++i) {
      int g = batch[r0 + i];
      if (g != gcur) {
        int* pf = (int*)&flat[(size_t)gcur * H_F + fq * 4];
        atomicMax(pf + 0, __float_as_int(mx.x));
        atomicMax(pf + 1, __float_as_int(mx.y));
        atomicMax(pf + 2, __float_as_int(mx.z));
        atomicMax(pf + 3, __float_as_int(mx.w));
        mx = make_float4(-INFINITY, -INFINITY, -INFINITY, -INFINITY);
        gcur = g;
        mm = *(const float4*)&msc[(size_t)gcur * H_F + fq * 4];
        ss = *(const float4*)&scale[(size_t)gcur * H_F + fq * 4];
      }
      size_t idx = (size_t)(r0 + i) * H_F + fq * 4;
      float4 v = *(const float4*)&h[idx];
      v.x = fmaxf((v.x - mm.x) * ss.x + bb.x, 0.f);
      v.y = fmaxf((v.y - mm.y) * ss.y + bb.y, 0.f);
      v.z = fmaxf((v.z - mm.z) * ss.z + bb.z, 0.f);
      v.w = fmaxf((v.w - mm.w) * ss.w + bb.w, 0.f);
      *(float4*)&h[idx] = v;
      mx.x = fmaxf(mx.x, v.x); mx.y = fmaxf(mx.y, v.y);
      mx.z = fmaxf(mx.z, v.z); mx.w = fmaxf(mx.w, v.w);
    }
    int* pf = (int*)&flat[(size_t)gcur * H_F + fq * 4];
    atomicMax(pf + 0, __float_as_int(mx.x));
    atomicMax(pf + 1, __float_as_int(mx.y));
    atomicMax(pf + 2, __float_as_int(mx.z));
    atomicMax(pf + 3, __float_as_int(mx.w));
    __syncthreads();
  }
}

// ---------------- passthrough copies ----------------
__global__ __launch_bounds__(256) void k_copy_i2f4(const int4* __restrict__ in,
                                                   float4* __restrict__ out, int n4) {
  int i = blockIdx.x * 256 + threadIdx.x;
  if (i < n4) {
    int4 v = in[i];
    out[i] = make_float4((float)v.x, (float)v.y, (float)v.z, (float)v.w);
  }
}
__global__ __launch_bounds__(256) void k_copy_f4(const float4* __restrict__ in,
                                                 float4* __restrict__ out, int n4) {
  int i = blockIdx.x * 256 + threadIdx.x;
  if (i < n4) out[i] = in[i];
}

extern "C" void kernel_launch(void* const* d_in, const int* in_sizes, int n_in,
                              void* d_out, int out_size, void* d_ws, size_t ws_size,
                              hipStream_t stream) {
  const float* inputs = (const float*)d_in[0];
  const int*   ei     = (const int*)d_in[1];
  const int*   batch  = (const int*)d_in[2];
  const float* eattr  = (const float*)d_in[3];
  const float* W1 = (const float*)d_in[4];
  const float* b1 = (const float*)d_in[5];
  const float* W2 = (const float*)d_in[6];
  const float* b2 = (const float*)d_in[7];
  const float* W3 = (const float*)d_in[8];
  const float* b3 = (const float*)d_in[9];
  const float* gw  = (const float*)d_in[10];
  const float* gb  = (const float*)d_in[11];
  const float* gms = (const float*)d_in[12];

  float* out = (float*)d_out;
  float* hemb  = out;                          // [100000,128]
  float* flat  = out + 12800000;               // [256,128]
  float* o_ei  = out + 12832768;               // [2,1600000]
  float* o_ea  = out + 16032768;               // [1600000,8]
  float* o_b   = out + 28832768;               // [100000]

  unsigned long long* binBuf = (unsigned long long*)hemb;
  unsigned short* xh = (unsigned short*)(hemb + 4200000);
  int*   csr   = (int*)o_ea;
  float* agg   = o_ea + 6400000;
  int*   cnt   = (int*)o_ei;
  int*   ovfc  = (int*)o_ei + 100000;
  int*   gbc   = (int*)o_ei + 100008;
  int*   ovf   = (int*)o_ei + 100032;
  float* gsum  = o_ei + 200000;
  float* gsumq = o_ei + 232768;
  float* msc   = o_ei + 265536;
  float* scl   = o_ei + 298304;

  hipMemsetAsync(cnt, 0, (N_NODES + 64) * sizeof(int), stream);
  hipMemsetAsync(gsum, 0, 2 * N_GRAPHS * H_F * sizeof(float), stream);
  k_cast<<<(N_NODES * IN_F / 4 + 255) / 256, 256, 0, stream>>>(
      (const float4*)inputs, (ushort4*)xh, N_NODES * IN_F / 4);
  k_bin<<<512, 256, 0, stream>>>(ei, ei + N_EDGES, binBuf, gbc);
  k_fill2<<<8 * 160, 256, 0, stream>>>(binBuf, gbc, csr, cnt, ovfc, ovf);
  k_gather<<<(N_NODES * 64 + 255) / 256, 256, 0, stream>>>(xh, csr, cnt, agg);
  k_ovf<<<16, 256, 0, stream>>>(ovf, ovfc, inputs, agg);
  const int gemmGrid = (N_NODES + 127) / 128;   // 782
  k_gemm1v2<<<gemmGrid, 256, 0, stream>>>(inputs, agg, W1, b1, hemb);
  k_gemmB<0><<<gemmGrid, 256, 0, stream>>>(hemb, W2, b2, hemb, batch, gsum, gsumq);
  k_gemmB<1><<<gemmGrid, 256, 0, stream>>>(hemb, W3, b3, hemb, batch, gsum, gsumq);
  k_finalize<<<N_GRAPHS, 128, 0, stream>>>(batch, gsum, gsumq, gms, gw, msc, scl, flat);
  k_apply<<<N_NODES / 32, 256, 0, stream>>>(hemb, batch, msc, scl, gb, flat);
  k_copy_i2f4<<<(2 * N_EDGES / 4 + 255) / 256, 256, 0, stream>>>((const int4*)ei, (float4*)o_ei, 2 * N_EDGES / 4);
  k_copy_f4<<<(N_EDGES * 2 + 255) / 256, 256, 0, stream>>>((const float4*)eattr, (float4*)o_ea, N_EDGES * 2);
  k_copy_i2f4<<<(N_NODES / 4 + 255) / 256, 256, 0, stream>>>((const int4*)batch, (float4*)o_b, N_NODES / 4);
}

// Round 8
// 338.412 us; speedup vs baseline: 1.0602x; 1.0602x over previous
//
#include <hip/hip_runtime.h>
#include <math.h>

#define N_NODES 100000
#define N_EDGES 1600000
#define N_GRAPHS 256
#define IN_F 64
#define H_F 128
#define GN_EPS 1e-5f
#define PAD 64
#define NBINS 8
#define LCAP 512
#define BINCAP (1 << 18)

__device__ __forceinline__ float bf2f(unsigned short u) {
  return __uint_as_float(((unsigned int)u) << 16);
}
__device__ __forceinline__ unsigned short f2bf(float f) {
  unsigned int u = __float_as_uint(f);
  u += 0x7FFFu + ((u >> 16) & 1u);
  return (unsigned short)(u >> 16);
}

// ---- cast x to bf16 (RTNE) ----
__global__ __launch_bounds__(256) void k_cast(const float4* __restrict__ in,
                                              ushort4* __restrict__ out, int n4) {
  int i = blockIdx.x * 256 + threadIdx.x;
  if (i < n4) {
    float4 v = in[i];
    ushort4 o;
    o.x = f2bf(v.x); o.y = f2bf(v.y); o.z = f2bf(v.z); o.w = f2bf(v.w);
    out[i] = o;
  }
}

// ---- phase A: LDS-staged radix partition of edges into 8 dst-range bins ----
__global__ __launch_bounds__(256) void k_bin(
    const int* __restrict__ src, const int* __restrict__ dst,
    unsigned long long* __restrict__ binBuf, int* __restrict__ gbc) {
  __shared__ unsigned long long ebuf[NBINS][LCAP];
  __shared__ int lcnt[NBINS];
  __shared__ int lbase[NBINS];
  const int t = threadIdx.x;
  if (t < NBINS) lcnt[t] = 0;
  __syncthreads();
  for (int e0 = blockIdx.x * 256; e0 < N_EDGES; e0 += gridDim.x * 256) {
    int e = e0 + t;
    if (e < N_EDGES) {
      int s = src[e], d = dst[e];
      int b = d / 12500;
      int p = atomicAdd(&lcnt[b], 1);
      ebuf[b][p] = ((unsigned long long)(unsigned)d << 32) | (unsigned)s;
    }
    __syncthreads();
    if (t < NBINS && lcnt[t] >= 256) lbase[t] = atomicAdd(&gbc[t], lcnt[t]);
    __syncthreads();
#pragma unroll
    for (int b = 0; b < NBINS; ++b) {
      int c = lcnt[b];
      if (c >= 256) {
        unsigned long long* gp = binBuf + (size_t)b * BINCAP + lbase[b];
        for (int i = t; i < c; i += 256) gp[i] = ebuf[b][i];
      }
    }
    __syncthreads();
    if (t < NBINS && lcnt[t] >= 256) lcnt[t] = 0;
    __syncthreads();
  }
  if (t < NBINS && lcnt[t] > 0) lbase[t] = atomicAdd(&gbc[t], lcnt[t]);
  __syncthreads();
#pragma unroll
  for (int b = 0; b < NBINS; ++b) {
    int c = lcnt[b];
    if (c > 0) {
      unsigned long long* gp = binBuf + (size_t)b * BINCAP + lbase[b];
      for (int i = t; i < c; i += 256) gp[i] = ebuf[b][i];
    }
  }
}

// ---- phase B: bucket fill, bin-per-XCD ----
__global__ __launch_bounds__(256) void k_fill2(
    const unsigned long long* __restrict__ binBuf, const int* __restrict__ gbc,
    int* __restrict__ csr, int* __restrict__ cnt,
    int* __restrict__ ovfc, int* __restrict__ ovf) {
  const int b = blockIdx.x & 7;
  const int nb = gbc[b];
  const unsigned long long* buf = binBuf + (size_t)b * BINCAP;
  const int stride = (gridDim.x >> 3) * 256;
  for (int i = (blockIdx.x >> 3) * 256 + threadIdx.x; i < nb; i += stride) {
    unsigned long long pk = buf[i];
    int d = (int)(pk >> 32), s = (int)(pk & 0xffffffffu);
    int pos = atomicAdd(&cnt[d], 1);
    if (pos < PAD) {
      csr[(size_t)d * PAD + pos] = s;
    } else {
      int o = atomicAdd(ovfc, 1);
      ovf[2 * o] = s;
      ovf[2 * o + 1] = d;
    }
  }
}

// ---- gather (bf16 x): wave per node; 16-lane group per src row ----
__global__ __launch_bounds__(256) void k_gather(
    const unsigned short* __restrict__ xh, const int* __restrict__ csr,
    const int* __restrict__ cnt, float* __restrict__ agg) {
  int wid = (blockIdx.x * 256 + threadIdx.x) >> 6;
  if (wid >= N_NODES) return;
  const int lane = threadIdx.x & 63;
  const int g = lane >> 4;
  const int fl = lane & 15;
  int deg = cnt[wid];
  if (deg > PAD) deg = PAD;
  int myE = csr[(size_t)wid * PAD + lane];
  float s0 = 0.f, s1 = 0.f, s2 = 0.f, s3 = 0.f;
  int j = g;
  for (; j + 4 < deg; j += 8) {
    int sA = __shfl(myE, j);
    int sB = __shfl(myE, j + 4);
    ushort4 a = *(const ushort4*)&xh[(size_t)sA * IN_F + fl * 4];
    ushort4 b = *(const ushort4*)&xh[(size_t)sB * IN_F + fl * 4];
    s0 += bf2f(a.x) + bf2f(b.x);
    s1 += bf2f(a.y) + bf2f(b.y);
    s2 += bf2f(a.z) + bf2f(b.z);
    s3 += bf2f(a.w) + bf2f(b.w);
  }
  if (j < deg) {
    int sA = __shfl(myE, j);
    ushort4 a = *(const ushort4*)&xh[(size_t)sA * IN_F + fl * 4];
    s0 += bf2f(a.x); s1 += bf2f(a.y); s2 += bf2f(a.z); s3 += bf2f(a.w);
  }
  s0 += __shfl_xor(s0, 16); s1 += __shfl_xor(s1, 16);
  s2 += __shfl_xor(s2, 16); s3 += __shfl_xor(s3, 16);
  s0 += __shfl_xor(s0, 32); s1 += __shfl_xor(s1, 32);
  s2 += __shfl_xor(s2, 32); s3 += __shfl_xor(s3, 32);
  if (g == 0) {
    float4 r = make_float4(s0, s1, s2, s3);
    *(float4*)&agg[(size_t)wid * IN_F + fl * 4] = r;
  }
}

// ---- overflow cleanup ----
__global__ __launch_bounds__(256) void k_ovf(
    const int* __restrict__ ovf, const int* __restrict__ ovfc,
    const float* __restrict__ x, float* __restrict__ agg) {
  int n = *ovfc;
  for (int idx = blockIdx.x * 256 + threadIdx.x; idx < n * 64; idx += gridDim.x * 256) {
    int o = idx >> 6, f = idx & 63;
    int s = ovf[2 * o], d = ovf[2 * o + 1];
    unsafeAtomicAdd(&agg[(size_t)d * IN_F + f], x[(size_t)s * IN_F + f]);
  }
}

// ========== GEMM v3: 32-row tile, 4x4/thread, row-major A (no transpose) ==========
// tm0=(t>>5)*4 rows, tn0=(t&31)*4 cols. A frags are k-vectorized float4 reads
// (2 broadcast addrs/wave, 16B aligned); W reads are consecutive-b128. Staging
// is direct float4 copies (dense 1KB block writes) -> no bank conflicts anywhere.

// ---- GEMM1: out = relu((x+agg) @ W1 + b1), K=64 ----
__global__ __launch_bounds__(256) void k_gemm1v3(
    const float* __restrict__ xin, const float* __restrict__ agg,
    const float* __restrict__ W, const float* __restrict__ bias,
    float* __restrict__ out) {
  __shared__ __align__(16) float As[32 * 68];    // 8.7 KB, row-major [m][k]
  __shared__ __align__(16) float Ws[64 * 128];   // 32 KB
  const int t = threadIdx.x;
  const int m0 = blockIdx.x * 32;
#pragma unroll
  for (int it = 0; it < 2; ++it) {
    int f4 = t + it * 256;         // 0..511 ; m = f4>>4, kq = f4&15
    int m = f4 >> 4, kq = f4 & 15;
    float4 a = *(const float4*)&xin[(size_t)(m0 + m) * IN_F + 4 * kq];
    float4 g = *(const float4*)&agg[(size_t)(m0 + m) * IN_F + 4 * kq];
    a.x += g.x; a.y += g.y; a.z += g.z; a.w += g.w;
    *(float4*)&As[m * 68 + 4 * kq] = a;
  }
#pragma unroll
  for (int it = 0; it < 8; ++it) {
    int f = t + it * 256;
    int k = f >> 5, nq = f & 31;
    *(float4*)&Ws[k * 128 + 4 * nq] = *(const float4*)&W[(size_t)k * H_F + 4 * nq];
  }
  __syncthreads();
  const int tm0 = (t >> 5) * 4, tn0 = (t & 31) * 4;
  float acc[4][4] = {};
#pragma unroll
  for (int kg = 0; kg < 16; ++kg) {
    float a[4][4], b[4][4];
#pragma unroll
    for (int i = 0; i < 4; ++i)
      *(float4*)&a[i][0] = *(const float4*)&As[(tm0 + i) * 68 + 4 * kg];
#pragma unroll
    for (int kk = 0; kk < 4; ++kk)
      *(float4*)&b[kk][0] = *(const float4*)&Ws[(4 * kg + kk) * 128 + tn0];
#pragma unroll
    for (int i = 0; i < 4; ++i)
#pragma unroll
      for (int kk = 0; kk < 4; ++kk) {
        float av = a[i][kk];
#pragma unroll
        for (int j = 0; j < 4; ++j) acc[i][j] += av * b[kk][j];
      }
  }
  float4 bv = *(const float4*)&bias[tn0];
#pragma unroll
  for (int i = 0; i < 4; ++i) {
    float4 r;
    r.x = fmaxf(acc[i][0] + bv.x, 0.f);
    r.y = fmaxf(acc[i][1] + bv.y, 0.f);
    r.z = fmaxf(acc[i][2] + bv.z, 0.f);
    r.w = fmaxf(acc[i][3] + bv.w, 0.f);
    *(float4*)&out[(size_t)(m0 + tm0 + i) * H_F + tn0] = r;
  }
}

// ---- GEMM K=128 (+optional fused GraphNorm stats) ----
template <int STATS>
__global__ __launch_bounds__(256) void k_gemmBv3(
    const float* __restrict__ in, const float* __restrict__ W,
    const float* __restrict__ bias, float* __restrict__ out,
    const int* __restrict__ batch, float* __restrict__ gsum,
    float* __restrict__ gsumsq) {
  __shared__ __align__(16) float As[32 * 132];   // 16.9 KB, row-major [m][k]
  __shared__ __align__(16) float Ws[64 * 128];   // 32 KB (half of W)
  const int t = threadIdx.x;
  const int m0 = blockIdx.x * 32;
#pragma unroll
  for (int it = 0; it < 4; ++it) {
    int f4 = t + it * 256;         // 0..1023 ; m = f4>>5, kq = f4&31
    int m = f4 >> 5, kq = f4 & 31;
    *(float4*)&As[m * 132 + 4 * kq] =
        *(const float4*)&in[(size_t)(m0 + m) * H_F + 4 * kq];
  }
  const int tm0 = (t >> 5) * 4, tn0 = (t & 31) * 4;
  float acc[4][4] = {};
  for (int kh = 0; kh < 2; ++kh) {
    __syncthreads();               // A-writes done (kh=0); Ws reads done (kh=1)
#pragma unroll
    for (int it = 0; it < 8; ++it) {
      int f = t + it * 256;
      int k = f >> 5, nq = f & 31;
      *(float4*)&Ws[k * 128 + 4 * nq] =
          *(const float4*)&W[(size_t)(kh * 64 + k) * H_F + 4 * nq];
    }
    __syncthreads();
#pragma unroll
    for (int kg = 0; kg < 16; ++kg) {
      float a[4][4], b[4][4];
#pragma unroll
      for (int i = 0; i < 4; ++i)
        *(float4*)&a[i][0] =
            *(const float4*)&As[(tm0 + i) * 132 + kh * 64 + 4 * kg];
#pragma unroll
      for (int kk = 0; kk < 4; ++kk)
        *(float4*)&b[kk][0] = *(const float4*)&Ws[(4 * kg + kk) * 128 + tn0];
#pragma unroll
      for (int i = 0; i < 4; ++i)
#pragma unroll
        for (int kk = 0; kk < 4; ++kk) {
          float av = a[i][kk];
#pragma unroll
          for (int j = 0; j < 4; ++j) acc[i][j] += av * b[kk][j];
        }
    }
  }
  float4 bv = *(const float4*)&bias[tn0];
#pragma unroll
  for (int i = 0; i < 4; ++i) {
    acc[i][0] = fmaxf(acc[i][0] + bv.x, 0.f);
    acc[i][1] = fmaxf(acc[i][1] + bv.y, 0.f);
    acc[i][2] = fmaxf(acc[i][2] + bv.z, 0.f);
    acc[i][3] = fmaxf(acc[i][3] + bv.w, 0.f);
    *(float4*)&out[(size_t)(m0 + tm0 + i) * H_F + tn0] = *(float4*)&acc[i][0];
  }
  if (STATS) {
    const int rg = t >> 5, fq = t & 31;
    const int glo = batch[m0];
    const int ghi = batch[m0 + 31];
    if (glo == ghi) {
      float4 s = {0,0,0,0}, q = {0,0,0,0};
#pragma unroll
      for (int i = 0; i < 4; ++i) {
        s.x += acc[i][0]; s.y += acc[i][1]; s.z += acc[i][2]; s.w += acc[i][3];
        q.x += acc[i][0] * acc[i][0]; q.y += acc[i][1] * acc[i][1];
        q.z += acc[i][2] * acc[i][2]; q.w += acc[i][3] * acc[i][3];
      }
      __syncthreads();               // done with As; reuse as scratch
      float4* sred = (float4*)&As[0];
      float4* qred = sred + 256;
      sred[rg * 32 + fq] = s;
      qred[rg * 32 + fq] = q;
      __syncthreads();
      if (rg == 0) {
        float4 S = {0,0,0,0}, Q = {0,0,0,0};
#pragma unroll
        for (int j = 0; j < 8; ++j) {
          float4 a0 = sred[j * 32 + fq], b0 = qred[j * 32 + fq];
          S.x += a0.x; S.y += a0.y; S.z += a0.z; S.w += a0.w;
          Q.x += b0.x; Q.y += b0.y; Q.z += b0.z; Q.w += b0.w;
        }
        float* ps = &gsum[(size_t)glo * H_F + fq * 4];
        float* pq = &gsumsq[(size_t)glo * H_F + fq * 4];
        unsafeAtomicAdd(ps + 0, S.x); unsafeAtomicAdd(ps + 1, S.y);
        unsafeAtomicAdd(ps + 2, S.z); unsafeAtomicAdd(ps + 3, S.w);
        unsafeAtomicAdd(pq + 0, Q.x); unsafeAtomicAdd(pq + 1, Q.y);
        unsafeAtomicAdd(pq + 2, Q.z); unsafeAtomicAdd(pq + 3, Q.w);
      }
    } else {
      int gcur = batch[m0 + tm0];
      float4 s = {0,0,0,0}, q = {0,0,0,0};
#pragma unroll
      for (int i = 0; i < 4; ++i) {
        int g = batch[m0 + tm0 + i];
        if (g != gcur) {
          float* ps = &gsum[(size_t)gcur * H_F + tn0];
          float* pq = &gsumsq[(size_t)gcur * H_F + tn0];
          unsafeAtomicAdd(ps + 0, s.x); unsafeAtomicAdd(ps + 1, s.y);
          unsafeAtomicAdd(ps + 2, s.z); unsafeAtomicAdd(ps + 3, s.w);
          unsafeAtomicAdd(pq + 0, q.x); unsafeAtomicAdd(pq + 1, q.y);
          unsafeAtomicAdd(pq + 2, q.z); unsafeAtomicAdd(pq + 3, q.w);
          s = make_float4(0, 0, 0, 0); q = make_float4(0, 0, 0, 0);
          gcur = g;
        }
        s.x += acc[i][0]; s.y += acc[i][1]; s.z += acc[i][2]; s.w += acc[i][3];
        q.x += acc[i][0] * acc[i][0]; q.y += acc[i][1] * acc[i][1];
        q.z += acc[i][2] * acc[i][2]; q.w += acc[i][3] * acc[i][3];
      }
      float* ps = &gsum[(size_t)gcur * H_F + tn0];
      float* pq = &gsumsq[(size_t)gcur * H_F + tn0];
      unsafeAtomicAdd(ps + 0, s.x); unsafeAtomicAdd(ps + 1, s.y);
      unsafeAtomicAdd(ps + 2, s.z); unsafeAtomicAdd(ps + 3, s.w);
      unsafeAtomicAdd(pq + 0, q.x); unsafeAtomicAdd(pq + 1, q.y);
      unsafeAtomicAdd(pq + 2, q.z); unsafeAtomicAdd(pq + 3, q.w);
    }
  }
}

// ---- finalize: per (graph,feature) shift/scale; init flat = -INF ----
__global__ __launch_bounds__(128) void k_finalize(
    const int* __restrict__ batch, const float* __restrict__ gsum,
    const float* __restrict__ gsumsq, const float* __restrict__ gms,
    const float* __restrict__ gw, float* __restrict__ msc,
    float* __restrict__ scale, float* __restrict__ flat) {
  const int g = blockIdx.x;
  const int f = threadIdx.x;
  __shared__ int sb[2];
  if (f < 2) {
    int target = g + f;
    int lo = 0, hi = N_NODES;
    while (lo < hi) { int mid = (lo + hi) >> 1; if (batch[mid] < target) lo = mid + 1; else hi = mid; }
    sb[f] = lo;
  }
  __syncthreads();
  float c = fmaxf((float)(sb[1] - sb[0]), 1.0f);
  float mean = gsum[(size_t)g * H_F + f] / c;
  float ms = mean * gms[f];
  float var = gsumsq[(size_t)g * H_F + f] / c - 2.0f * ms * mean + ms * ms;
  var = fmaxf(var, 0.0f);
  msc[(size_t)g * H_F + f] = ms;
  scale[(size_t)g * H_F + f] = gw[f] * rsqrtf(var + GN_EPS);
  flat[(size_t)g * H_F + f] = -INFINITY;
}

// ---- apply: h = relu((h - msc)*scale + gb); flat = segment max ----
__global__ __launch_bounds__(256) void k_apply(
    float* __restrict__ h, const int* __restrict__ batch,
    const float* __restrict__ msc, const float* __restrict__ scale,
    const float* __restrict__ gb, float* __restrict__ flat) {
  const int t = threadIdx.x;
  const int rg = t >> 5, fq = t & 31;
  const int m0 = blockIdx.x * 32;
  const int r0 = m0 + rg * 4;
  const float4 bb = *(const float4*)&gb[fq * 4];
  const int glo = batch[m0], ghi = batch[m0 + 31];
  __shared__ __align__(16) float4 mred[8][32];
  if (glo == ghi) {
    const float4 m = *(const float4*)&msc[(size_t)glo * H_F + fq * 4];
    const float4 sc = *(const float4*)&scale[(size_t)glo * H_F + fq * 4];
    float4 mx = {-INFINITY, -INFINITY, -INFINITY, -INFINITY};
#pragma unroll
    for (int i = 0; i < 4; ++i) {
      size_t idx = (size_t)(r0 + i) * H_F + fq * 4;
      float4 v = *(const float4*)&h[idx];
      v.x = fmaxf((v.x - m.x) * sc.x + bb.x, 0.f);
      v.y = fmaxf((v.y - m.y) * sc.y + bb.y, 0.f);
      v.z = fmaxf((v.z - m.z) * sc.z + bb.z, 0.f);
      v.w = fmaxf((v.w - m.w) * sc.w + bb.w, 0.f);
      *(float4*)&h[idx] = v;
      mx.x = fmaxf(mx.x, v.x); mx.y = fmaxf(mx.y, v.y);
      mx.z = fmaxf(mx.z, v.z); mx.w = fmaxf(mx.w, v.w);
    }
    mred[rg][fq] = mx;
    __syncthreads();
    if (rg == 0) {
#pragma unroll
      for (int j = 1; j < 8; ++j) {
        float4 a = mred[j][fq];
        mx.x = fmaxf(mx.x, a.x); mx.y = fmaxf(mx.y, a.y);
        mx.z = fmaxf(mx.z, a.z); mx.w = fmaxf(mx.w, a.w);
      }
      int* pf = (int*)&flat[(size_t)glo * H_F + fq * 4];
      atomicMax(pf + 0, __float_as_int(mx.x));
      atomicMax(pf + 1, __float_as_int(mx.y));
      atomicMax(pf + 2, __float_as_int(mx.z));
      atomicMax(pf + 3, __float_as_int(mx.w));
    }
  } else {
    int gcur = batch[r0];
    float4 mm = *(const float4*)&msc[(size_t)gcur * H_F + fq * 4];
    float4 ss = *(const float4*)&scale[(size_t)gcur * H_F + fq * 4];
    float4 mx = {-INFINITY, -INFINITY, -INFINITY, -INFINITY};
#pragma unroll
    for (int i = 0; i < 4; ++i) {
      int g = batch[r0 + i];
      if (g != gcur) {
        int* pf = (int*)&flat[(size_t)gcur * H_F + fq * 4];
        atomicMax(pf + 0, __float_as_int(mx.x));
        atomicMax(pf + 1, __float_as_int(mx.y));
        atomicMax(pf + 2, __float_as_int(mx.z));
        atomicMax(pf + 3, __float_as_int(mx.w));
        mx = make_float4(-INFINITY, -INFINITY, -INFINITY, -INFINITY);
        gcur = g;
        mm = *(const float4*)&msc[(size_t)gcur * H_F + fq * 4];
        ss = *(const float4*)&scale[(size_t)gcur * H_F + fq * 4];
      }
      size_t idx = (size_t)(r0 + i) * H_F + fq * 4;
      float4 v = *(const float4*)&h[idx];
      v.x = fmaxf((v.x - mm.x) * ss.x + bb.x, 0.f);
      v.y = fmaxf((v.y - mm.y) * ss.y + bb.y, 0.f);
      v.z = fmaxf((v.z - mm.z) * ss.z + bb.z, 0.f);
      v.w = fmaxf((v.w - mm.w) * ss.w + bb.w, 0.f);
      *(float4*)&h[idx] = v;
      mx.x = fmaxf(mx.x, v.x); mx.y = fmaxf(mx.y, v.y);
      mx.z = fmaxf(mx.z, v.z); mx.w = fmaxf(mx.w, v.w);
    }
    int* pf = (int*)&flat[(size_t)gcur * H_F + fq * 4];
    atomicMax(pf + 0, __float_as_int(mx.x));
    atomicMax(pf + 1, __float_as_int(mx.y));
    atomicMax(pf + 2, __float_as_int(mx.z));
    atomicMax(pf + 3, __float_as_int(mx.w));
    __syncthreads();
  }
}

// ---------------- passthrough copies ----------------
__global__ __launch_bounds__(256) void k_copy_i2f4(const int4* __restrict__ in,
                                                   float4* __restrict__ out, int n4) {
  int i = blockIdx.x * 256 + threadIdx.x;
  if (i < n4) {
    int4 v = in[i];
    out[i] = make_float4((float)v.x, (float)v.y, (float)v.z, (float)v.w);
  }
}
__global__ __launch_bounds__(256) void k_copy_f4(const float4* __restrict__ in,
                                                 float4* __restrict__ out, int n4) {
  int i = blockIdx.x * 256 + threadIdx.x;
  if (i < n4) out[i] = in[i];
}

extern "C" void kernel_launch(void* const* d_in, const int* in_sizes, int n_in,
                              void* d_out, int out_size, void* d_ws, size_t ws_size,
                              hipStream_t stream) {
  const float* inputs = (const float*)d_in[0];
  const int*   ei     = (const int*)d_in[1];
  const int*   batch  = (const int*)d_in[2];
  const float* eattr  = (const float*)d_in[3];
  const float* W1 = (const float*)d_in[4];
  const float* b1 = (const float*)d_in[5];
  const float* W2 = (const float*)d_in[6];
  const float* b2 = (const float*)d_in[7];
  const float* W3 = (const float*)d_in[8];
  const float* b3 = (const float*)d_in[9];
  const float* gw  = (const float*)d_in[10];
  const float* gb  = (const float*)d_in[11];
  const float* gms = (const float*)d_in[12];

  float* out = (float*)d_out;
  float* hemb  = out;                          // [100000,128]
  float* flat  = out + 12800000;               // [256,128]
  float* o_ei  = out + 12832768;               // [2,1600000]
  float* o_ea  = out + 16032768;               // [1600000,8]
  float* o_b   = out + 28832768;               // [100000]

  unsigned long long* binBuf = (unsigned long long*)hemb;
  unsigned short* xh = (unsigned short*)(hemb + 4200000);
  int*   csr   = (int*)o_ea;
  float* agg   = o_ea + 6400000;
  int*   cnt   = (int*)o_ei;
  int*   ovfc  = (int*)o_ei + 100000;
  int*   gbc   = (int*)o_ei + 100008;
  int*   ovf   = (int*)o_ei + 100032;
  float* gsum  = o_ei + 200000;
  float* gsumq = o_ei + 232768;
  float* msc   = o_ei + 265536;
  float* scl   = o_ei + 298304;

  hipMemsetAsync(cnt, 0, (N_NODES + 64) * sizeof(int), stream);
  hipMemsetAsync(gsum, 0, 2 * N_GRAPHS * H_F * sizeof(float), stream);
  k_cast<<<(N_NODES * IN_F / 4 + 255) / 256, 256, 0, stream>>>(
      (const float4*)inputs, (ushort4*)xh, N_NODES * IN_F / 4);
  k_bin<<<512, 256, 0, stream>>>(ei, ei + N_EDGES, binBuf, gbc);
  k_fill2<<<8 * 160, 256, 0, stream>>>(binBuf, gbc, csr, cnt, ovfc, ovf);
  k_gather<<<(N_NODES * 64 + 255) / 256, 256, 0, stream>>>(xh, csr, cnt, agg);
  k_ovf<<<16, 256, 0, stream>>>(ovf, ovfc, inputs, agg);
  const int gemmGrid = N_NODES / 32;   // 3125
  k_gemm1v3<<<gemmGrid, 256, 0, stream>>>(inputs, agg, W1, b1, hemb);
  k_gemmBv3<0><<<gemmGrid, 256, 0, stream>>>(hemb, W2, b2, hemb, batch, gsum, gsumq);
  k_gemmBv3<1><<<gemmGrid, 256, 0, stream>>>(hemb, W3, b3, hemb, batch, gsum, gsumq);
  k_finalize<<<N_GRAPHS, 128, 0, stream>>>(batch, gsum, gsumq, gms, gw, msc, scl, flat);
  k_apply<<<N_NODES / 32, 256, 0, stream>>>(hemb, batch, msc, scl, gb, flat);
  k_copy_i2f4<<<(2 * N_EDGES / 4 + 255) / 256, 256, 0, stream>>>((const int4*)ei, (float4*)o_ei, 2 * N_EDGES / 4);
  k_copy_f4<<<(N_EDGES * 2 + 255) / 256, 256, 0, stream>>>((const float4*)eattr, (float4*)o_ea, N_EDGES * 2);
  k_copy_i2f4<<<(N_NODES / 4 + 255) / 256, 256, 0, stream>>>((const int4*)batch, (float4*)o_b, N_NODES / 4);
}

// Round 9
// 337.300 us; speedup vs baseline: 1.0637x; 1.0033x over previous
//
#include <hip/hip_runtime.h>
#include <math.h>

#define N_NODES 100000
#define N_EDGES 1600000
#define N_GRAPHS 256
#define IN_F 64
#define H_F 128
#define GN_EPS 1e-5f
#define PAD 64
#define NBINS 8
#define LCAP 512
#define BINCAP (1 << 18)

typedef __attribute__((ext_vector_type(8))) short bf16x8;
typedef __attribute__((ext_vector_type(4))) float f32x4;

__device__ __forceinline__ float bf2f(unsigned short u) {
  return __uint_as_float(((unsigned int)u) << 16);
}
__device__ __forceinline__ unsigned short f2bf(float f) {
  unsigned int u = __float_as_uint(f);
  u += 0x7FFFu + ((u >> 16) & 1u);
  return (unsigned short)(u >> 16);
}

// ---- cast x to bf16 (RTNE) ----
__global__ __launch_bounds__(256) void k_cast(const float4* __restrict__ in,
                                              ushort4* __restrict__ out, int n4) {
  int i = blockIdx.x * 256 + threadIdx.x;
  if (i < n4) {
    float4 v = in[i];
    ushort4 o;
    o.x = f2bf(v.x); o.y = f2bf(v.y); o.z = f2bf(v.z); o.w = f2bf(v.w);
    out[i] = o;
  }
}

// ---- pre-transpose weights to bf16 Wt[n][k] ----
__global__ __launch_bounds__(256) void k_prepW(
    const float* __restrict__ W1, const float* __restrict__ W2,
    const float* __restrict__ W3, unsigned short* __restrict__ wt) {
  int i = blockIdx.x * 256 + threadIdx.x;   // 40960 total
  if (i < 8192) {                            // Wt1 [128][64]
    int n = i >> 6, k = i & 63;
    wt[i] = f2bf(W1[(size_t)k * H_F + n]);
  } else if (i < 24576) {                    // Wt2 [128][128]
    int j = i - 8192;
    int n = j >> 7, k = j & 127;
    wt[i] = f2bf(W2[(size_t)k * H_F + n]);
  } else if (i < 40960) {                    // Wt3 [128][128]
    int j = i - 24576;
    int n = j >> 7, k = j & 127;
    wt[i] = f2bf(W3[(size_t)k * H_F + n]);
  }
}

// ---- phase A: LDS-staged radix partition of edges into 8 dst-range bins ----
__global__ __launch_bounds__(256) void k_bin(
    const int* __restrict__ src, const int* __restrict__ dst,
    unsigned long long* __restrict__ binBuf, int* __restrict__ gbc) {
  __shared__ unsigned long long ebuf[NBINS][LCAP];
  __shared__ int lcnt[NBINS];
  __shared__ int lbase[NBINS];
  const int t = threadIdx.x;
  if (t < NBINS) lcnt[t] = 0;
  __syncthreads();
  for (int e0 = blockIdx.x * 256; e0 < N_EDGES; e0 += gridDim.x * 256) {
    int e = e0 + t;
    if (e < N_EDGES) {
      int s = src[e], d = dst[e];
      int b = d / 12500;
      int p = atomicAdd(&lcnt[b], 1);
      ebuf[b][p] = ((unsigned long long)(unsigned)d << 32) | (unsigned)s;
    }
    __syncthreads();
    if (t < NBINS && lcnt[t] >= 256) lbase[t] = atomicAdd(&gbc[t], lcnt[t]);
    __syncthreads();
#pragma unroll
    for (int b = 0; b < NBINS; ++b) {
      int c = lcnt[b];
      if (c >= 256) {
        unsigned long long* gp = binBuf + (size_t)b * BINCAP + lbase[b];
        for (int i = t; i < c; i += 256) gp[i] = ebuf[b][i];
      }
    }
    __syncthreads();
    if (t < NBINS && lcnt[t] >= 256) lcnt[t] = 0;
    __syncthreads();
  }
  if (t < NBINS && lcnt[t] > 0) lbase[t] = atomicAdd(&gbc[t], lcnt[t]);
  __syncthreads();
#pragma unroll
  for (int b = 0; b < NBINS; ++b) {
    int c = lcnt[b];
    if (c > 0) {
      unsigned long long* gp = binBuf + (size_t)b * BINCAP + lbase[b];
      for (int i = t; i < c; i += 256) gp[i] = ebuf[b][i];
    }
  }
}

// ---- phase B: bucket fill, bin-per-XCD ----
__global__ __launch_bounds__(256) void k_fill2(
    const unsigned long long* __restrict__ binBuf, const int* __restrict__ gbc,
    int* __restrict__ csr, int* __restrict__ cnt,
    int* __restrict__ ovfc, int* __restrict__ ovf) {
  const int b = blockIdx.x & 7;
  const int nb = gbc[b];
  const unsigned long long* buf = binBuf + (size_t)b * BINCAP;
  const int stride = (gridDim.x >> 3) * 256;
  for (int i = (blockIdx.x >> 3) * 256 + threadIdx.x; i < nb; i += stride) {
    unsigned long long pk = buf[i];
    int d = (int)(pk >> 32), s = (int)(pk & 0xffffffffu);
    int pos = atomicAdd(&cnt[d], 1);
    if (pos < PAD) {
      csr[(size_t)d * PAD + pos] = s;
    } else {
      int o = atomicAdd(ovfc, 1);
      ovf[2 * o] = s;
      ovf[2 * o + 1] = d;
    }
  }
}

// ---- gather: xa = x + sum_neighbors, bf16 out ----
__global__ __launch_bounds__(256) void k_gather(
    const unsigned short* __restrict__ xh, const int* __restrict__ csr,
    const int* __restrict__ cnt, unsigned short* __restrict__ xa) {
  int wid = (blockIdx.x * 256 + threadIdx.x) >> 6;
  if (wid >= N_NODES) return;
  const int lane = threadIdx.x & 63;
  const int g = lane >> 4;
  const int fl = lane & 15;
  int deg = cnt[wid];
  if (deg > PAD) deg = PAD;
  int myE = csr[(size_t)wid * PAD + lane];
  float s0 = 0.f, s1 = 0.f, s2 = 0.f, s3 = 0.f;
  int j = g;
  for (; j + 4 < deg; j += 8) {
    int sA = __shfl(myE, j);
    int sB = __shfl(myE, j + 4);
    ushort4 a = *(const ushort4*)&xh[(size_t)sA * IN_F + fl * 4];
    ushort4 b = *(const ushort4*)&xh[(size_t)sB * IN_F + fl * 4];
    s0 += bf2f(a.x) + bf2f(b.x);
    s1 += bf2f(a.y) + bf2f(b.y);
    s2 += bf2f(a.z) + bf2f(b.z);
    s3 += bf2f(a.w) + bf2f(b.w);
  }
  if (j < deg) {
    int sA = __shfl(myE, j);
    ushort4 a = *(const ushort4*)&xh[(size_t)sA * IN_F + fl * 4];
    s0 += bf2f(a.x); s1 += bf2f(a.y); s2 += bf2f(a.z); s3 += bf2f(a.w);
  }
  s0 += __shfl_xor(s0, 16); s1 += __shfl_xor(s1, 16);
  s2 += __shfl_xor(s2, 16); s3 += __shfl_xor(s3, 16);
  s0 += __shfl_xor(s0, 32); s1 += __shfl_xor(s1, 32);
  s2 += __shfl_xor(s2, 32); s3 += __shfl_xor(s3, 32);
  if (g == 0) {
    ushort4 self = *(const ushort4*)&xh[(size_t)wid * IN_F + fl * 4];
    s0 += bf2f(self.x); s1 += bf2f(self.y);
    s2 += bf2f(self.z); s3 += bf2f(self.w);
    ushort4 r;
    r.x = f2bf(s0); r.y = f2bf(s1); r.z = f2bf(s2); r.w = f2bf(s3);
    *(ushort4*)&xa[(size_t)wid * IN_F + fl * 4] = r;
  }
}

// ---- overflow fixup (deg > PAD; expected n==0). One block, lane = feature:
// each thread owns feature f for all overflow edges -> race-free sequential RMW.
__global__ __launch_bounds__(64) void k_ovf2(
    const int* __restrict__ ovf, const int* __restrict__ ovfc,
    const float* __restrict__ x, unsigned short* __restrict__ xa) {
  int n = *ovfc;
  int f = threadIdx.x;
  for (int o = 0; o < n; ++o) {
    int s = ovf[2 * o], d = ovf[2 * o + 1];
    size_t idx = (size_t)d * IN_F + f;
    xa[idx] = f2bf(bf2f(xa[idx]) + x[(size_t)s * IN_F + f]);
  }
}

// ========== MFMA GEMM: LDS-free, 4 waves x 16 rows, N=128 ==========
// A [M][K] bf16, Wt [128][K] bf16 (W transposed). Per wave: A-frags 16B/lane
// direct from global; 8 n-tiles x (K/32) mfma_f32_16x16x32_bf16.
// C/D layout: col = lane&15, row = (lane>>4)*4 + reg [verified m89].
template <int K, int OUTF32>
__global__ __launch_bounds__(256) void k_mfma(
    const unsigned short* __restrict__ A,
    const unsigned short* __restrict__ Wt,
    const float* __restrict__ bias,
    unsigned short* __restrict__ outh,
    float* __restrict__ outf) {
  const int t = threadIdx.x;
  const int lane = t & 63;
  const int wv = t >> 6;
  const int row16 = lane & 15;
  const int kg = lane >> 4;          // 0..3
  const int NS = K / 32;
  const long r0 = (long)blockIdx.x * 64 + wv * 16;
  long arow = r0 + row16;
  if (arow > N_NODES - 1) arow = N_NODES - 1;
  const unsigned short* ap = A + arow * K + kg * 8;
  bf16x8 a[K / 32];
#pragma unroll
  for (int s = 0; s < NS; ++s) a[s] = *(const bf16x8*)(ap + s * 32);
  f32x4 acc[8];
#pragma unroll
  for (int n = 0; n < 8; ++n) acc[n] = (f32x4){0.f, 0.f, 0.f, 0.f};
  const unsigned short* wp = Wt + (size_t)row16 * K + kg * 8;
#pragma unroll
  for (int n = 0; n < 8; ++n) {
    const unsigned short* wpn = wp + (size_t)n * 16 * K;
    bf16x8 b[K / 32];
#pragma unroll
    for (int s = 0; s < NS; ++s) b[s] = *(const bf16x8*)(wpn + s * 32);
#pragma unroll
    for (int s = 0; s < NS; ++s)
      acc[n] = __builtin_amdgcn_mfma_f32_16x16x32_bf16(a[s], b[s], acc[n], 0, 0, 0);
  }
#pragma unroll
  for (int n = 0; n < 8; ++n) {
    int col = n * 16 + row16;
    float bv = bias[col];
#pragma unroll
    for (int r = 0; r < 4; ++r) {
      long row = r0 + kg * 4 + r;
      if (row < N_NODES) {
        float v = fmaxf(acc[n][r] + bv, 0.f);
        if (OUTF32) outf[row * H_F + col] = v;
        else        outh[row * H_F + col] = f2bf(v);
      }
    }
  }
}

// ---- standalone GraphNorm stats over h3 fp32 (32-row blocks) ----
__global__ __launch_bounds__(256) void k_stats(
    const float* __restrict__ h, const int* __restrict__ batch,
    float* __restrict__ gsum, float* __restrict__ gsumsq) {
  __shared__ __align__(16) float4 sred[256];
  __shared__ __align__(16) float4 qred[256];
  const int t = threadIdx.x;
  const int m0 = blockIdx.x * 32;
  const int tm0 = (t >> 5) * 4, tn0 = (t & 31) * 4;
  const int rg = t >> 5, fq = t & 31;
  float4 v[4];
#pragma unroll
  for (int i = 0; i < 4; ++i)
    v[i] = *(const float4*)&h[(size_t)(m0 + tm0 + i) * H_F + tn0];
  const int glo = batch[m0];
  const int ghi = batch[m0 + 31];
  if (glo == ghi) {
    float4 s = {0,0,0,0}, q = {0,0,0,0};
#pragma unroll
    for (int i = 0; i < 4; ++i) {
      s.x += v[i].x; s.y += v[i].y; s.z += v[i].z; s.w += v[i].w;
      q.x += v[i].x * v[i].x; q.y += v[i].y * v[i].y;
      q.z += v[i].z * v[i].z; q.w += v[i].w * v[i].w;
    }
    sred[rg * 32 + fq] = s;
    qred[rg * 32 + fq] = q;
    __syncthreads();
    if (rg == 0) {
      float4 S = {0,0,0,0}, Q = {0,0,0,0};
#pragma unroll
      for (int j = 0; j < 8; ++j) {
        float4 a0 = sred[j * 32 + fq], b0 = qred[j * 32 + fq];
        S.x += a0.x; S.y += a0.y; S.z += a0.z; S.w += a0.w;
        Q.x += b0.x; Q.y += b0.y; Q.z += b0.z; Q.w += b0.w;
      }
      float* ps = &gsum[(size_t)glo * H_F + fq * 4];
      float* pq = &gsumsq[(size_t)glo * H_F + fq * 4];
      unsafeAtomicAdd(ps + 0, S.x); unsafeAtomicAdd(ps + 1, S.y);
      unsafeAtomicAdd(ps + 2, S.z); unsafeAtomicAdd(ps + 3, S.w);
      unsafeAtomicAdd(pq + 0, Q.x); unsafeAtomicAdd(pq + 1, Q.y);
      unsafeAtomicAdd(pq + 2, Q.z); unsafeAtomicAdd(pq + 3, Q.w);
    }
  } else {
    int gcur = batch[m0 + tm0];
    float4 s = {0,0,0,0}, q = {0,0,0,0};
#pragma unroll
    for (int i = 0; i < 4; ++i) {
      int g = batch[m0 + tm0 + i];
      if (g != gcur) {
        float* ps = &gsum[(size_t)gcur * H_F + tn0];
        float* pq = &gsumsq[(size_t)gcur * H_F + tn0];
        unsafeAtomicAdd(ps + 0, s.x); unsafeAtomicAdd(ps + 1, s.y);
        unsafeAtomicAdd(ps + 2, s.z); unsafeAtomicAdd(ps + 3, s.w);
        unsafeAtomicAdd(pq + 0, q.x); unsafeAtomicAdd(pq + 1, q.y);
        unsafeAtomicAdd(pq + 2, q.z); unsafeAtomicAdd(pq + 3, q.w);
        s = make_float4(0, 0, 0, 0); q = make_float4(0, 0, 0, 0);
        gcur = g;
      }
      s.x += v[i].x; s.y += v[i].y; s.z += v[i].z; s.w += v[i].w;
      q.x += v[i].x * v[i].x; q.y += v[i].y * v[i].y;
      q.z += v[i].z * v[i].z; q.w += v[i].w * v[i].w;
    }
    float* ps = &gsum[(size_t)gcur * H_F + tn0];
    float* pq = &gsumsq[(size_t)gcur * H_F + tn0];
    unsafeAtomicAdd(ps + 0, s.x); unsafeAtomicAdd(ps + 1, s.y);
    unsafeAtomicAdd(ps + 2, s.z); unsafeAtomicAdd(ps + 3, s.w);
    unsafeAtomicAdd(pq + 0, q.x); unsafeAtomicAdd(pq + 1, q.y);
    unsafeAtomicAdd(pq + 2, q.z); unsafeAtomicAdd(pq + 3, q.w);
  }
}

// ---- finalize: per (graph,feature) shift/scale; init flat = -INF ----
__global__ __launch_bounds__(128) void k_finalize(
    const int* __restrict__ batch, const float* __restrict__ gsum,
    const float* __restrict__ gsumsq, const float* __restrict__ gms,
    const float* __restrict__ gw, float* __restrict__ msc,
    float* __restrict__ scale, float* __restrict__ flat) {
  const int g = blockIdx.x;
  const int f = threadIdx.x;
  __shared__ int sb[2];
  if (f < 2) {
    int target = g + f;
    int lo = 0, hi = N_NODES;
    while (lo < hi) { int mid = (lo + hi) >> 1; if (batch[mid] < target) lo = mid + 1; else hi = mid; }
    sb[f] = lo;
  }
  __syncthreads();
  float c = fmaxf((float)(sb[1] - sb[0]), 1.0f);
  float mean = gsum[(size_t)g * H_F + f] / c;
  float ms = mean * gms[f];
  float var = gsumsq[(size_t)g * H_F + f] / c - 2.0f * ms * mean + ms * ms;
  var = fmaxf(var, 0.0f);
  msc[(size_t)g * H_F + f] = ms;
  scale[(size_t)g * H_F + f] = gw[f] * rsqrtf(var + GN_EPS);
  flat[(size_t)g * H_F + f] = -INFINITY;
}

// ---- apply: h = relu((h - msc)*scale + gb); flat = segment max ----
__global__ __launch_bounds__(256) void k_apply(
    float* __restrict__ h, const int* __restrict__ batch,
    const float* __restrict__ msc, const float* __restrict__ scale,
    const float* __restrict__ gb, float* __restrict__ flat) {
  const int t = threadIdx.x;
  const int rg = t >> 5, fq = t & 31;
  const int m0 = blockIdx.x * 32;
  const int r0 = m0 + rg * 4;
  const float4 bb = *(const float4*)&gb[fq * 4];
  const int glo = batch[m0], ghi = batch[m0 + 31];
  __shared__ __align__(16) float4 mred[8][32];
  if (glo == ghi) {
    const float4 m = *(const float4*)&msc[(size_t)glo * H_F + fq * 4];
    const float4 sc = *(const float4*)&scale[(size_t)glo * H_F + fq * 4];
    float4 mx = {-INFINITY, -INFINITY, -INFINITY, -INFINITY};
#pragma unroll
    for (int i = 0; i < 4; ++i) {
      size_t idx = (size_t)(r0 + i) * H_F + fq * 4;
      float4 v = *(const float4*)&h[idx];
      v.x = fmaxf((v.x - m.x) * sc.x + bb.x, 0.f);
      v.y = fmaxf((v.y - m.y) * sc.y + bb.y, 0.f);
      v.z = fmaxf((v.z - m.z) * sc.z + bb.z, 0.f);
      v.w = fmaxf((v.w - m.w) * sc.w + bb.w, 0.f);
      *(float4*)&h[idx] = v;
      mx.x = fmaxf(mx.x, v.x); mx.y = fmaxf(mx.y, v.y);
      mx.z = fmaxf(mx.z, v.z); mx.w = fmaxf(mx.w, v.w);
    }
    mred[rg][fq] = mx;
    __syncthreads();
    if (rg == 0) {
#pragma unroll
      for (int j = 1; j < 8; ++j) {
        float4 a = mred[j][fq];
        mx.x = fmaxf(mx.x, a.x); mx.y = fmaxf(mx.y, a.y);
        mx.z = fmaxf(mx.z, a.z); mx.w = fmaxf(mx.w, a.w);
      }
      int* pf = (int*)&flat[(size_t)glo * H_F + fq * 4];
      atomicMax(pf + 0, __float_as_int(mx.x));
      atomicMax(pf + 1, __float_as_int(mx.y));
      atomicMax(pf + 2, __float_as_int(mx.z));
      atomicMax(pf + 3, __float_as_int(mx.w));
    }
  } else {
    int gcur = batch[r0];
    float4 mm = *(const float4*)&msc[(size_t)gcur * H_F + fq * 4];
    float4 ss = *(const float4*)&scale[(size_t)gcur * H_F + fq * 4];
    float4 mx = {-INFINITY, -INFINITY, -INFINITY, -INFINITY};
#pragma unroll
    for (int i = 0; i < 4; ++i) {
      int g = batch[r0 + i];
      if (g != gcur) {
        int* pf = (int*)&flat[(size_t)gcur * H_F + fq * 4];
        atomicMax(pf + 0, __float_as_int(mx.x));
        atomicMax(pf + 1, __float_as_int(mx.y));
        atomicMax(pf + 2, __float_as_int(mx.z));
        atomicMax(pf + 3, __float_as_int(mx.w));
        mx = make_float4(-INFINITY, -INFINITY, -INFINITY, -INFINITY);
        gcur = g;
        mm = *(const float4*)&msc[(size_t)gcur * H_F + fq * 4];
        ss = *(const float4*)&scale[(size_t)gcur * H_F + fq * 4];
      }
      size_t idx = (size_t)(r0 + i) * H_F + fq * 4;
      float4 v = *(const float4*)&h[idx];
      v.x = fmaxf((v.x - mm.x) * ss.x + bb.x, 0.f);
      v.y = fmaxf((v.y - mm.y) * ss.y + bb.y, 0.f);
      v.z = fmaxf((v.z - mm.z) * ss.z + bb.z, 0.f);
      v.w = fmaxf((v.w - mm.w) * ss.w + bb.w, 0.f);
      *(float4*)&h[idx] = v;
      mx.x = fmaxf(mx.x, v.x); mx.y = fmaxf(mx.y, v.y);
      mx.z = fmaxf(mx.z, v.z); mx.w = fmaxf(mx.w, v.w);
    }
    int* pf = (int*)&flat[(size_t)gcur * H_F + fq * 4];
    atomicMax(pf + 0, __float_as_int(mx.x));
    atomicMax(pf + 1, __float_as_int(mx.y));
    atomicMax(pf + 2, __float_as_int(mx.z));
    atomicMax(pf + 3, __float_as_int(mx.w));
    __syncthreads();
  }
}

// ---------------- passthrough copies ----------------
__global__ __launch_bounds__(256) void k_copy_i2f4(const int4* __restrict__ in,
                                                   float4* __restrict__ out, int n4) {
  int i = blockIdx.x * 256 + threadIdx.x;
  if (i < n4) {
    int4 v = in[i];
    out[i] = make_float4((float)v.x, (float)v.y, (float)v.z, (float)v.w);
  }
}
__global__ __launch_bounds__(256) void k_copy_f4(const float4* __restrict__ in,
                                                 float4* __restrict__ out, int n4) {
  int i = blockIdx.x * 256 + threadIdx.x;
  if (i < n4) out[i] = in[i];
}

extern "C" void kernel_launch(void* const* d_in, const int* in_sizes, int n_in,
                              void* d_out, int out_size, void* d_ws, size_t ws_size,
                              hipStream_t stream) {
  const float* inputs = (const float*)d_in[0];
  const int*   ei     = (const int*)d_in[1];
  const int*   batch  = (const int*)d_in[2];
  const float* eattr  = (const float*)d_in[3];
  const float* W1 = (const float*)d_in[4];
  const float* b1 = (const float*)d_in[5];
  const float* W2 = (const float*)d_in[6];
  const float* b2 = (const float*)d_in[7];
  const float* W3 = (const float*)d_in[8];
  const float* b3 = (const float*)d_in[9];
  const float* gw  = (const float*)d_in[10];
  const float* gb  = (const float*)d_in[11];
  const float* gms = (const float*)d_in[12];

  float* out = (float*)d_out;
  float* hemb  = out;                          // [100000,128] fp32
  float* flat  = out + 12800000;               // [256,128]
  float* o_ei  = out + 12832768;               // [2,1600000]
  float* o_ea  = out + 16032768;               // [1600000,8]
  float* o_b   = out + 28832768;               // [100000]

  // Scratch (all dead before their region is finally written):
  //  hemb region: binBuf @0 (16MB), xh bf16 @4.2M floats, xa bf16 @7.6M floats
  //               -> all dead before k_mfma3 writes hemb
  //  o_ea region: csr @0 (25.6MB) -> h2 bf16 after gather; h1 bf16 @6.4M floats
  //  o_ei region: cnt/ovfc/gbc/ovf + gsum/gsumq/msc/scl + Wt bf16 @350000
  unsigned long long* binBuf = (unsigned long long*)hemb;
  unsigned short* xh = (unsigned short*)(hemb + 4200000);
  unsigned short* xa = (unsigned short*)(hemb + 7600000);
  int*            csr = (int*)o_ea;
  unsigned short* h2  = (unsigned short*)o_ea;            // reuses csr after gather
  unsigned short* h1  = (unsigned short*)(o_ea + 6400000);
  int*   cnt   = (int*)o_ei;
  int*   ovfc  = (int*)o_ei + 100000;
  int*   gbc   = (int*)o_ei + 100008;
  int*   ovf   = (int*)o_ei + 100032;
  float* gsum  = o_ei + 200000;
  float* gsumq = o_ei + 232768;
  float* msc   = o_ei + 265536;
  float* scl   = o_ei + 298304;
  unsigned short* wt  = (unsigned short*)(o_ei + 350000); // 40960 bf16
  unsigned short* wt1 = wt;
  unsigned short* wt2 = wt + 8192;
  unsigned short* wt3 = wt + 24576;

  hipMemsetAsync(cnt, 0, (N_NODES + 64) * sizeof(int), stream);
  hipMemsetAsync(gsum, 0, 2 * N_GRAPHS * H_F * sizeof(float), stream);
  k_prepW<<<160, 256, 0, stream>>>(W1, W2, W3, wt);
  k_cast<<<(N_NODES * IN_F / 4 + 255) / 256, 256, 0, stream>>>(
      (const float4*)inputs, (ushort4*)xh, N_NODES * IN_F / 4);
  k_bin<<<512, 256, 0, stream>>>(ei, ei + N_EDGES, binBuf, gbc);
  k_fill2<<<8 * 160, 256, 0, stream>>>(binBuf, gbc, csr, cnt, ovfc, ovf);
  k_gather<<<(N_NODES * 64 + 255) / 256, 256, 0, stream>>>(xh, csr, cnt, xa);
  k_ovf2<<<1, 64, 0, stream>>>(ovf, ovfc, inputs, xa);
  const int mg = (N_NODES + 63) / 64;   // 1563
  k_mfma<64, 0><<<mg, 256, 0, stream>>>(xa, wt1, b1, h1, nullptr);
  k_mfma<128, 0><<<mg, 256, 0, stream>>>(h1, wt2, b2, h2, nullptr);
  k_mfma<128, 1><<<mg, 256, 0, stream>>>(h2, wt3, b3, nullptr, hemb);
  k_stats<<<N_NODES / 32, 256, 0, stream>>>(hemb, batch, gsum, gsumq);
  k_finalize<<<N_GRAPHS, 128, 0, stream>>>(batch, gsum, gsumq, gms, gw, msc, scl, flat);
  k_apply<<<N_NODES / 32, 256, 0, stream>>>(hemb, batch, msc, scl, gb, flat);
  k_copy_i2f4<<<(2 * N_EDGES / 4 + 255) / 256, 256, 0, stream>>>((const int4*)ei, (float4*)o_ei, 2 * N_EDGES / 4);
  k_copy_f4<<<(N_EDGES * 2 + 255) / 256, 256, 0, stream>>>((const float4*)eattr, (float4*)o_ea, N_EDGES * 2);
  k_copy_i2f4<<<(N_NODES / 4 + 255) / 256, 256, 0, stream>>>((const int4*)batch, (float4*)o_b, N_NODES / 4);
}